// Round 1
// baseline (773.400 us; speedup 1.0000x reference)
//
#include <hip/hip_runtime.h>

// Cube2Equirec bilinear resample.
// x:    [6*E, C, L, L] f32   (E=2, C=32, L=512)  = 384 MB
// face: [H, W] i32           (H=512, W=1024)
// xy:   [H, W, 2] f32        (u, v) already clipped to [0, L-1]
// out:  [E, C, H, W] f32     = 128 MB
//
// One thread per equirect pixel; indices/weights computed once, reused
// across all E*C = 64 channel images. Stores coalesced along w.

constexpr int L  = 512;
constexpr int LL = L * L;
constexpr int H  = 512;
constexpr int W  = 1024;
constexpr int HW = H * W;
constexpr int E  = 2;
constexpr int C  = 32;

__global__ __launch_bounds__(256, 8) void c2e_kernel(
    const float* __restrict__ x,
    const int*   __restrict__ face,
    const float* __restrict__ xy,
    float*       __restrict__ out)
{
    const int pix = blockIdx.x * 256 + threadIdx.x;   // 0 .. HW-1

    const int f = face[pix];
    const float2 uv = reinterpret_cast<const float2*>(xy)[pix];
    const float u = uv.x, v = uv.y;

    int x0 = (int)floorf(u); x0 = min(max(x0, 0), L - 1);
    int y0 = (int)floorf(v); y0 = min(max(y0, 0), L - 1);
    const int x1 = min(x0 + 1, L - 1);
    const int y1 = min(y0 + 1, L - 1);

    const float wx = u - (float)x0;
    const float wy = v - (float)y0;
    const float w00 = (1.f - wx) * (1.f - wy);
    const float w01 = wx * (1.f - wy);
    const float w10 = (1.f - wx) * wy;
    const float w11 = wx * wy;

    const int o00 = y0 * L + x0;
    const int o01 = y0 * L + x1;
    const int o10 = y1 * L + x0;
    const int o11 = y1 * L + x1;

    #pragma unroll
    for (int e = 0; e < E; ++e) {
        const float* __restrict__ xin = x + (size_t)((e * 6 + f) * C) * LL;
        float* __restrict__ op = out + (size_t)(e * C) * HW + pix;
        #pragma unroll 4
        for (int c = 0; c < C; ++c) {
            const float* p = xin + (size_t)c * LL;
            const float s = w00 * p[o00] + w01 * p[o01]
                          + w10 * p[o10] + w11 * p[o11];
            op[(size_t)c * HW] = s;
        }
    }
}

extern "C" void kernel_launch(void* const* d_in, const int* in_sizes, int n_in,
                              void* d_out, int out_size, void* d_ws, size_t ws_size,
                              hipStream_t stream) {
    const float* x    = (const float*)d_in[0];
    const int*   face = (const int*)d_in[1];
    const float* xy   = (const float*)d_in[2];
    float*       out  = (float*)d_out;

    c2e_kernel<<<dim3(HW / 256), dim3(256), 0, stream>>>(x, face, xy, out);
}

// Round 5
// 704.307 us; speedup vs baseline: 1.0981x; 1.0981x over previous
//
#include <hip/hip_runtime.h>

// Cube2Equirec bilinear resample.
// x:    [6*E, C, L, L] f32   (E=2, C=32, L=512)  = 384 MB
// face: [H, W] i32           (H=512, W=1024)
// xy:   [H, W, 2] f32        (u, v) already clipped to [0, L-1]
// out:  [E, C, H, W] f32     = 128 MB
//
// Thread = (pixel, 8-channel chunk). Per thread: 32 independent dword
// gathers issued back-to-back (max MLP), then 8 coalesced stores.
// grid = (HW/256, 8): blockIdx.y selects (e, c-base) chunk.

constexpr int L   = 512;
constexpr int LL  = L * L;
constexpr int H   = 512;
constexpr int W   = 1024;
constexpr int HW  = H * W;
constexpr int C   = 32;
constexpr int ECP = 8;   // channels per thread

__global__ __launch_bounds__(256, 8) void c2e_kernel(
    const float* __restrict__ x,
    const int*   __restrict__ face,
    const float* __restrict__ xy,
    float*       __restrict__ out)
{
    const int pix = blockIdx.x * 256 + threadIdx.x;   // 0 .. HW-1
    const int e     = blockIdx.y >> 2;                // 0..1
    const int cbase = (blockIdx.y & 3) * ECP;         // 0,8,16,24

    const int f = face[pix];
    const float2 uv = reinterpret_cast<const float2*>(xy)[pix];
    const float u = uv.x, v = uv.y;

    int x0 = (int)floorf(u); x0 = min(max(x0, 0), L - 1);
    int y0 = (int)floorf(v); y0 = min(max(y0, 0), L - 1);
    const int x1 = min(x0 + 1, L - 1);
    const int y1 = min(y0 + 1, L - 1);

    const float wx = u - (float)x0;
    const float wy = v - (float)y0;
    const float w00 = (1.f - wx) * (1.f - wy);
    const float w01 = wx * (1.f - wy);
    const float w10 = (1.f - wx) * wy;
    const float w11 = wx * wy;

    const int y0L = y0 * L;
    const int y1L = y1 * L;
    const int o00 = y0L + x0;
    const int o01 = y0L + x1;
    const int o10 = y1L + x0;
    const int o11 = y1L + x1;

    // base plane: image (e*6+f), channel cbase
    const float* __restrict__ base = x + (size_t)((e * 6 + f) * C + cbase) * LL;

    float v00[ECP], v01[ECP], v10[ECP], v11[ECP];
    #pragma unroll
    for (int i = 0; i < ECP; ++i) {
        const float* p = base + (size_t)i * LL;
        v00[i] = p[o00];
        v01[i] = p[o01];
        v10[i] = p[o10];
        v11[i] = p[o11];
    }

    float* __restrict__ op = out + (size_t)(e * C + cbase) * HW + pix;
    #pragma unroll
    for (int i = 0; i < ECP; ++i) {
        op[(size_t)i * HW] = w00 * v00[i] + w01 * v01[i]
                           + w10 * v10[i] + w11 * v11[i];
    }
}

extern "C" void kernel_launch(void* const* d_in, const int* in_sizes, int n_in,
                              void* d_out, int out_size, void* d_ws, size_t ws_size,
                              hipStream_t stream) {
    const float* x    = (const float*)d_in[0];
    const int*   face = (const int*)d_in[1];
    const float* xy   = (const float*)d_in[2];
    float*       out  = (float*)d_out;

    c2e_kernel<<<dim3(HW / 256, 8), dim3(256), 0, stream>>>(x, face, xy, out);
}